// Round 4
// baseline (246.162 us; speedup 1.0000x reference)
//
#include <hip/hip_runtime.h>
#include <math.h>

// HumanPoseModule: per-element rotation pipeline.
// glb_reduced_6d: (BT, 10, 6) f32 ; orientation_6d: (BT, 6, 6) f32
// out: (BT, 24, 3) f32
//
// R4 = R1 structure (bulk float4 input load burst -> MLP; aa[] SSA scalars;
// clustered float4 store tail -> no partial-line write amplification)
//    + R2 math (rsq/rcp, no libm atan2/sin, argmax on pre-sqrt values)
//    + __launch_bounds__(256, 4): grid is only 4096 waves = 4 waves/SIMD max,
//      so a 128-VGPR cap costs no achievable occupancy but stops the
//      allocator from spilling (R2's failure: default waves/EU target ->
//      scratch round-trips, +170MB HBM traffic).

__device__ __forceinline__ void rot6d(const float* __restrict__ d, float M[3][3]) {
    float a1x = d[0], a1y = d[1], a1z = d[2];
    float a2x = d[3], a2y = d[4], a2z = d[5];
    float r1 = __builtin_amdgcn_rsqf(a1x * a1x + a1y * a1y + a1z * a1z);
    float b1x = a1x * r1, b1y = a1y * r1, b1z = a1z * r1;
    float dt = b1x * a2x + b1y * a2y + b1z * a2z;
    float c2x = a2x - dt * b1x, c2y = a2y - dt * b1y, c2z = a2z - dt * b1z;
    float r2 = __builtin_amdgcn_rsqf(c2x * c2x + c2y * c2y + c2z * c2z);
    float b2x = c2x * r2, b2y = c2y * r2, b2z = c2z * r2;
    float b3x = b1y * b2z - b1z * b2y;
    float b3y = b1z * b2x - b1x * b2z;
    float b3z = b1x * b2y - b1y * b2x;
    M[0][0] = b1x; M[0][1] = b1y; M[0][2] = b1z;
    M[1][0] = b2x; M[1][1] = b2y; M[1][2] = b2z;
    M[2][0] = b3x; M[2][1] = b3y; M[2][2] = b3z;
}

// C = A @ B
__device__ __forceinline__ void matmul(const float A[3][3], const float B[3][3], float C[3][3]) {
#pragma unroll
    for (int i = 0; i < 3; ++i)
#pragma unroll
        for (int j = 0; j < 3; ++j)
            C[i][j] = A[i][0] * B[0][j] + A[i][1] * B[1][j] + A[i][2] * B[2][j];
}

// C = A^T @ B
__device__ __forceinline__ void matTmul(const float A[3][3], const float B[3][3], float C[3][3]) {
#pragma unroll
    for (int i = 0; i < 3; ++i)
#pragma unroll
        for (int j = 0; j < 3; ++j)
            C[i][j] = A[0][i] * B[0][j] + A[1][i] * B[1][j] + A[2][i] * B[2][j];
}

// atan2(y,x) for y >= 0, result in [0, pi]. Minimax atan poly on [0,1], err ~2e-8.
__device__ __forceinline__ float atan2_pos(float y, float x) {
    float ax = fabsf(x);
    float mx = fmaxf(y, ax);
    float mn = fminf(y, ax);
    float a = mn * __builtin_amdgcn_rcpf(mx);
    float s = a * a;
    float p = -0.0040540580f;
    p = fmaf(p, s, 0.0218612288f);
    p = fmaf(p, s, -0.0559098861f);
    p = fmaf(p, s, 0.0964200441f);
    p = fmaf(p, s, -0.1390853351f);
    p = fmaf(p, s, 0.1994653599f);
    p = fmaf(p, s, -0.3332985605f);
    p = fmaf(p, s, 0.9999993329f);
    float r = p * a;
    r = (y > ax) ? (1.5707963268f - r) : r;
    r = (x < 0.f) ? (3.1415926536f - r) : r;
    return r;
}

__device__ __forceinline__ void mat2aa(const float m[3][3], float* __restrict__ out) {
    float m00 = m[0][0], m01 = m[0][1], m02 = m[0][2];
    float m10 = m[1][0], m11 = m[1][1], m12 = m[1][2];
    float m20 = m[2][0], m21 = m[2][1], m22 = m[2][2];
    float t0 = fmaxf(1.f + m00 + m11 + m22, 0.f);
    float t1 = fmaxf(1.f + m00 - m11 - m22, 0.f);
    float t2 = fmaxf(1.f - m00 + m11 - m22, 0.f);
    float t3 = fmaxf(1.f - m00 - m11 + m22, 0.f);
    // argmax over t == argmax over sqrt(t) (monotonic, same first-max ties)
    int idx = 0;
    float bt = t0;
    if (t1 > bt) { bt = t1; idx = 1; }
    if (t2 > bt) { bt = t2; idx = 2; }
    if (t3 > bt) { bt = t3; idx = 3; }
    float best = __builtin_amdgcn_sqrtf(bt);  // >= 1 always (sum of t == 4)
    float s1 = m21 - m12, s2 = m02 - m20, s3 = m10 - m01;
    float p1 = m10 + m01, p2 = m02 + m20, p3 = m12 + m21;
    float w = (idx == 0) ? bt : (idx == 1) ? s1 : (idx == 2) ? s2 : s3;
    float x = (idx == 0) ? s1 : (idx == 1) ? bt : (idx == 2) ? p1 : p2;
    float y = (idx == 0) ? s2 : (idx == 1) ? p1 : (idx == 2) ? bt : p3;
    float z = (idx == 0) ? s3 : (idx == 1) ? p2 : (idx == 2) ? p3 : bt;
    float inv = 0.5f * __builtin_amdgcn_rcpf(fmaxf(best, 0.1f));
    w *= inv; x *= inv; y *= inv; z *= inv;
    // unit quaternion: sin(half) == |v|, cos(half) == w
    float n = __builtin_amdgcn_sqrtf(x * x + y * y + z * z);
    float half = atan2_pos(n, w);
    float angle = 2.f * half;
    // angle < 1e-6 => ref's (0.5 - angle^2/48) rounds to 0.5 => inv_sh = 2
    float inv_sh = (angle < 1e-6f) ? 2.f : angle * __builtin_amdgcn_rcpf(n);
    out[0] = x * inv_sh;
    out[1] = y * inv_sh;
    out[2] = z * inv_sh;
}

__global__ __launch_bounds__(256, 4) void pose_kernel(const float* __restrict__ glb,
                                                      const float* __restrict__ ori,
                                                      float* __restrict__ out, int BT) {
    int e = blockIdx.x * blockDim.x + threadIdx.x;
    if (e >= BT) return;

    // ---- bulk input load: 24 dwordx4 issued as one MLP burst ----
    float g[60];
    {
        const float4* gp = (const float4*)(glb + (size_t)e * 60);
#pragma unroll
        for (int i = 0; i < 15; ++i) {
            float4 v = gp[i];
            g[4 * i + 0] = v.x; g[4 * i + 1] = v.y; g[4 * i + 2] = v.z; g[4 * i + 3] = v.w;
        }
    }
    float o[36];
    {
        const float4* op = (const float4*)(ori + (size_t)e * 36);
#pragma unroll
        for (int i = 0; i < 9; ++i) {
            float4 v = op[i];
            o[4 * i + 0] = v.x; o[4 * i + 1] = v.y; o[4 * i + 2] = v.z; o[4 * i + 3] = v.w;
        }
    }

    float aa[72];
#pragma unroll
    for (int j3 = 0; j3 < 3; ++j3) {
        aa[7 * 3 + j3] = 0.f;  aa[8 * 3 + j3] = 0.f;
        aa[10 * 3 + j3] = 0.f; aa[11 * 3 + j3] = 0.f;
        aa[20 * 3 + j3] = 0.f; aa[21 * 3 + j3] = 0.f;
        aa[22 * 3 + j3] = 0.f; aa[23 * 3 + j3] = 0.f;
    }

    float root[3][3];
    rot6d(o + 0, root);
    mat2aa(root, aa + 0);  // joint 0

    float T[3][3], Fa[3][3], Fb[3][3], Fc[3][3], L[3][3];

#define FULL_R(k, DST) { rot6d(g + (k) * 6, T); matmul(root, T, DST); }
#define FULL_O(s, DST) { rot6d(o + (s) * 6, T); matmul(root, T, DST); }
#define LOCAL_OUT(P, C, joint) { matTmul(P, C, L); mat2aa(L, aa + (joint) * 3); }

    // arm: 1 -> 4
    FULL_R(0, Fa);               // F1
    LOCAL_OUT(root, Fa, 1);
    FULL_O(1, Fb);               // F4
    LOCAL_OUT(Fa, Fb, 4);
    // arm: 2 -> 5
    FULL_R(1, Fa);               // F2
    LOCAL_OUT(root, Fa, 2);
    FULL_O(2, Fb);               // F5
    LOCAL_OUT(Fa, Fb, 5);
    // spine: 3 -> 6 -> 9
    FULL_R(2, Fa);               // F3
    LOCAL_OUT(root, Fa, 3);
    FULL_R(3, Fb);               // F6
    LOCAL_OUT(Fa, Fb, 6);
    FULL_R(4, Fa);               // F9
    LOCAL_OUT(Fb, Fa, 9);
    // from F9 (Fa): 12 -> 15
    FULL_R(5, Fb);               // F12
    LOCAL_OUT(Fa, Fb, 12);
    FULL_O(3, Fc);               // F15
    LOCAL_OUT(Fb, Fc, 15);
    // from F9: 13 -> 16 -> 18
    FULL_R(6, Fb);               // F13
    LOCAL_OUT(Fa, Fb, 13);
    FULL_R(8, Fc);               // F16
    LOCAL_OUT(Fb, Fc, 16);
    FULL_O(4, Fb);               // F18
    LOCAL_OUT(Fc, Fb, 18);
    // from F9: 14 -> 17 -> 19
    FULL_R(7, Fb);               // F14
    LOCAL_OUT(Fa, Fb, 14);
    FULL_R(9, Fc);               // F17
    LOCAL_OUT(Fb, Fc, 17);
    FULL_O(5, Fb);               // F19
    LOCAL_OUT(Fc, Fb, 19);

#undef FULL_R
#undef FULL_O
#undef LOCAL_OUT

    // ---- clustered store tail: 18 dwordx4, lines complete quickly ----
    float4* outp = (float4*)(out + (size_t)e * 72);
#pragma unroll
    for (int i = 0; i < 18; ++i) {
        float4 v;
        v.x = aa[4 * i + 0]; v.y = aa[4 * i + 1]; v.z = aa[4 * i + 2]; v.w = aa[4 * i + 3];
        outp[i] = v;
    }
}

extern "C" void kernel_launch(void* const* d_in, const int* in_sizes, int n_in,
                              void* d_out, int out_size, void* d_ws, size_t ws_size,
                              hipStream_t stream) {
    const float* glb = (const float*)d_in[0];   // (BT,10,6) f32
    const float* ori = (const float*)d_in[1];   // (BT,6,6)  f32
    float* out = (float*)d_out;                 // (BT,24,3) f32
    int BT = in_sizes[0] / 60;
    int block = 256;
    int grid = (BT + block - 1) / block;
    pose_kernel<<<grid, block, 0, stream>>>(glb, ori, out, BT);
}

// Round 5
// 185.389 us; speedup vs baseline: 1.3278x; 1.3278x over previous
//
#include <hip/hip_runtime.h>
#include <math.h>

// HumanPoseModule: per-element rotation pipeline.
// glb_reduced_6d: (BT, 10, 6) f32 ; orientation_6d: (BT, 6, 6) f32
// out: (BT, 24, 3) f32
//
// R5 = R2 (bulk float4 input burst; cheap rsq/rcp/poly math; aa[] SSA;
// clustered float4 store tail; plain __launch_bounds__(256) — R4's second
// arg made the allocator over-squeeze to 64 VGPR and spill 250MB) plus
// __builtin_amdgcn_sched_barrier(0) after each joint: R2's spills came from
// the scheduler interleaving joints (cheap chains -> aggressive hoisting ->
// live-range blowup at VGPR 80). Barriers pin R1's program order, whose live
// set is proven to fit (R1: 76 VGPR, zero spill), with ~2.5x cheaper math.

__device__ __forceinline__ void rot6d(const float* __restrict__ d, float M[3][3]) {
    float a1x = d[0], a1y = d[1], a1z = d[2];
    float a2x = d[3], a2y = d[4], a2z = d[5];
    float r1 = __builtin_amdgcn_rsqf(a1x * a1x + a1y * a1y + a1z * a1z);
    float b1x = a1x * r1, b1y = a1y * r1, b1z = a1z * r1;
    float dt = b1x * a2x + b1y * a2y + b1z * a2z;
    float c2x = a2x - dt * b1x, c2y = a2y - dt * b1y, c2z = a2z - dt * b1z;
    float r2 = __builtin_amdgcn_rsqf(c2x * c2x + c2y * c2y + c2z * c2z);
    float b2x = c2x * r2, b2y = c2y * r2, b2z = c2z * r2;
    float b3x = b1y * b2z - b1z * b2y;
    float b3y = b1z * b2x - b1x * b2z;
    float b3z = b1x * b2y - b1y * b2x;
    M[0][0] = b1x; M[0][1] = b1y; M[0][2] = b1z;
    M[1][0] = b2x; M[1][1] = b2y; M[1][2] = b2z;
    M[2][0] = b3x; M[2][1] = b3y; M[2][2] = b3z;
}

// C = A @ B
__device__ __forceinline__ void matmul(const float A[3][3], const float B[3][3], float C[3][3]) {
#pragma unroll
    for (int i = 0; i < 3; ++i)
#pragma unroll
        for (int j = 0; j < 3; ++j)
            C[i][j] = A[i][0] * B[0][j] + A[i][1] * B[1][j] + A[i][2] * B[2][j];
}

// C = A^T @ B
__device__ __forceinline__ void matTmul(const float A[3][3], const float B[3][3], float C[3][3]) {
#pragma unroll
    for (int i = 0; i < 3; ++i)
#pragma unroll
        for (int j = 0; j < 3; ++j)
            C[i][j] = A[0][i] * B[0][j] + A[1][i] * B[1][j] + A[2][i] * B[2][j];
}

// atan2(y,x) for y >= 0, result in [0, pi]. Minimax atan poly on [0,1], err ~2e-8.
__device__ __forceinline__ float atan2_pos(float y, float x) {
    float ax = fabsf(x);
    float mx = fmaxf(y, ax);
    float mn = fminf(y, ax);
    float a = mn * __builtin_amdgcn_rcpf(mx);
    float s = a * a;
    float p = -0.0040540580f;
    p = fmaf(p, s, 0.0218612288f);
    p = fmaf(p, s, -0.0559098861f);
    p = fmaf(p, s, 0.0964200441f);
    p = fmaf(p, s, -0.1390853351f);
    p = fmaf(p, s, 0.1994653599f);
    p = fmaf(p, s, -0.3332985605f);
    p = fmaf(p, s, 0.9999993329f);
    float r = p * a;
    r = (y > ax) ? (1.5707963268f - r) : r;
    r = (x < 0.f) ? (3.1415926536f - r) : r;
    return r;
}

__device__ __forceinline__ void mat2aa(const float m[3][3], float* __restrict__ out) {
    float m00 = m[0][0], m01 = m[0][1], m02 = m[0][2];
    float m10 = m[1][0], m11 = m[1][1], m12 = m[1][2];
    float m20 = m[2][0], m21 = m[2][1], m22 = m[2][2];
    float t0 = fmaxf(1.f + m00 + m11 + m22, 0.f);
    float t1 = fmaxf(1.f + m00 - m11 - m22, 0.f);
    float t2 = fmaxf(1.f - m00 + m11 - m22, 0.f);
    float t3 = fmaxf(1.f - m00 - m11 + m22, 0.f);
    // argmax over t == argmax over sqrt(t) (monotonic, same first-max ties)
    int idx = 0;
    float bt = t0;
    if (t1 > bt) { bt = t1; idx = 1; }
    if (t2 > bt) { bt = t2; idx = 2; }
    if (t3 > bt) { bt = t3; idx = 3; }
    float best = __builtin_amdgcn_sqrtf(bt);  // >= 1 always (sum of t == 4)
    float s1 = m21 - m12, s2 = m02 - m20, s3 = m10 - m01;
    float p1 = m10 + m01, p2 = m02 + m20, p3 = m12 + m21;
    float w = (idx == 0) ? bt : (idx == 1) ? s1 : (idx == 2) ? s2 : s3;
    float x = (idx == 0) ? s1 : (idx == 1) ? bt : (idx == 2) ? p1 : p2;
    float y = (idx == 0) ? s2 : (idx == 1) ? p1 : (idx == 2) ? bt : p3;
    float z = (idx == 0) ? s3 : (idx == 1) ? p2 : (idx == 2) ? p3 : bt;
    float inv = 0.5f * __builtin_amdgcn_rcpf(fmaxf(best, 0.1f));
    w *= inv; x *= inv; y *= inv; z *= inv;
    // unit quaternion: sin(half) == |v|, cos(half) == w
    float n = __builtin_amdgcn_sqrtf(x * x + y * y + z * z);
    float half = atan2_pos(n, w);
    float angle = 2.f * half;
    // angle < 1e-6 => ref's (0.5 - angle^2/48) rounds to 0.5 => inv_sh = 2
    float inv_sh = (angle < 1e-6f) ? 2.f : angle * __builtin_amdgcn_rcpf(n);
    out[0] = x * inv_sh;
    out[1] = y * inv_sh;
    out[2] = z * inv_sh;
}

__global__ __launch_bounds__(256) void pose_kernel(const float* __restrict__ glb,
                                                   const float* __restrict__ ori,
                                                   float* __restrict__ out, int BT) {
    int e = blockIdx.x * blockDim.x + threadIdx.x;
    if (e >= BT) return;

    // ---- bulk input load: 24 dwordx4 issued as one MLP burst ----
    float g[60];
    {
        const float4* gp = (const float4*)(glb + (size_t)e * 60);
#pragma unroll
        for (int i = 0; i < 15; ++i) {
            float4 v = gp[i];
            g[4 * i + 0] = v.x; g[4 * i + 1] = v.y; g[4 * i + 2] = v.z; g[4 * i + 3] = v.w;
        }
    }
    float o[36];
    {
        const float4* op = (const float4*)(ori + (size_t)e * 36);
#pragma unroll
        for (int i = 0; i < 9; ++i) {
            float4 v = op[i];
            o[4 * i + 0] = v.x; o[4 * i + 1] = v.y; o[4 * i + 2] = v.z; o[4 * i + 3] = v.w;
        }
    }

    float aa[72];

    float root[3][3];
    rot6d(o + 0, root);
    mat2aa(root, aa + 0);  // joint 0
    __builtin_amdgcn_sched_barrier(0);

    float T[3][3], Fa[3][3], Fb[3][3], Fc[3][3], L[3][3];

#define FULL_R(k, DST) { rot6d(g + (k) * 6, T); matmul(root, T, DST); }
#define FULL_O(s, DST) { rot6d(o + (s) * 6, T); matmul(root, T, DST); }
#define LOCAL_OUT(P, C, joint) { matTmul(P, C, L); mat2aa(L, aa + (joint) * 3); \
                                 __builtin_amdgcn_sched_barrier(0); }

    // arm: 1 -> 4
    FULL_R(0, Fa);               // F1
    LOCAL_OUT(root, Fa, 1);
    FULL_O(1, Fb);               // F4
    LOCAL_OUT(Fa, Fb, 4);
    // arm: 2 -> 5
    FULL_R(1, Fa);               // F2
    LOCAL_OUT(root, Fa, 2);
    FULL_O(2, Fb);               // F5
    LOCAL_OUT(Fa, Fb, 5);
    // spine: 3 -> 6 -> 9
    FULL_R(2, Fa);               // F3
    LOCAL_OUT(root, Fa, 3);
    FULL_R(3, Fb);               // F6
    LOCAL_OUT(Fa, Fb, 6);
    FULL_R(4, Fa);               // F9
    LOCAL_OUT(Fb, Fa, 9);
    // from F9 (Fa): 12 -> 15
    FULL_R(5, Fb);               // F12
    LOCAL_OUT(Fa, Fb, 12);
    FULL_O(3, Fc);               // F15
    LOCAL_OUT(Fb, Fc, 15);
    // from F9: 13 -> 16 -> 18
    FULL_R(6, Fb);               // F13
    LOCAL_OUT(Fa, Fb, 13);
    FULL_R(8, Fc);               // F16
    LOCAL_OUT(Fb, Fc, 16);
    FULL_O(4, Fb);               // F18
    LOCAL_OUT(Fc, Fb, 18);
    // from F9: 14 -> 17 -> 19
    FULL_R(7, Fb);               // F14
    LOCAL_OUT(Fa, Fb, 14);
    FULL_R(9, Fc);               // F17
    LOCAL_OUT(Fb, Fc, 17);
    FULL_O(5, Fb);               // F19
    LOCAL_OUT(Fc, Fb, 19);

#undef FULL_R
#undef FULL_O
#undef LOCAL_OUT

    // ignored joints -> exact zeros, materialized only at the store tail
#pragma unroll
    for (int j3 = 0; j3 < 3; ++j3) {
        aa[7 * 3 + j3] = 0.f;  aa[8 * 3 + j3] = 0.f;
        aa[10 * 3 + j3] = 0.f; aa[11 * 3 + j3] = 0.f;
        aa[20 * 3 + j3] = 0.f; aa[21 * 3 + j3] = 0.f;
        aa[22 * 3 + j3] = 0.f; aa[23 * 3 + j3] = 0.f;
    }

    // ---- clustered store tail: 18 dwordx4, lines complete quickly ----
    float4* outp = (float4*)(out + (size_t)e * 72);
#pragma unroll
    for (int i = 0; i < 18; ++i) {
        float4 v;
        v.x = aa[4 * i + 0]; v.y = aa[4 * i + 1]; v.z = aa[4 * i + 2]; v.w = aa[4 * i + 3];
        outp[i] = v;
    }
}

extern "C" void kernel_launch(void* const* d_in, const int* in_sizes, int n_in,
                              void* d_out, int out_size, void* d_ws, size_t ws_size,
                              hipStream_t stream) {
    const float* glb = (const float*)d_in[0];   // (BT,10,6) f32
    const float* ori = (const float*)d_in[1];   // (BT,6,6)  f32
    float* out = (float*)d_out;                 // (BT,24,3) f32
    int BT = in_sizes[0] / 60;
    int block = 256;
    int grid = (BT + block - 1) / block;
    pose_kernel<<<grid, block, 0, stream>>>(glb, ori, out, BT);
}

// Round 6
// 152.407 us; speedup vs baseline: 1.6152x; 1.2164x over previous
//
#include <hip/hip_runtime.h>
#include <math.h>

// HumanPoseModule: (BT,10,6) + (BT,6,6) f32 -> (BT,24,3) f32 axis-angle.
//
// R6: ONE LANE PER JOINT (16 lanes/element). Reference identity:
// full[j] = root @ rot6d(src_j) for EVERY joint (chain enters only via
// local[j] = full[parent]^T @ full[j]), so all 16 output joints are
// independent given root. Each lane recomputes root and its parent's full
// matrix with the bitwise-identical fp sequence the chained version used.
// R5 was latency-bound (VALUBusy 21%, 3 waves/SIMD, one ~16x600cyc serial
// chain per wave); this gives 16x more waves and 16x shorter chains for
// ~1.6x extra total VALU work.
//
// Lane tables (byte-packed u64s; lane l = tid&15):
//   joints: {0,1,2,3,4,5,6,9,12,13,14,15,16,17,18,19} (= non-ignored set)
//   srcj:   sel<<4|row  (sel 0 = glb row, 1 = ori row)
//   pr1:    0 -> parent is root; else parent's glb row + 1
// Ignored joints {7,8,10,11,20,21,22,23} -> zeros, written by lanes 0-7.

__device__ __forceinline__ void rot6d(const float* __restrict__ d, float M[3][3]) {
    float a1x = d[0], a1y = d[1], a1z = d[2];
    float a2x = d[3], a2y = d[4], a2z = d[5];
    float r1 = __builtin_amdgcn_rsqf(a1x * a1x + a1y * a1y + a1z * a1z);
    float b1x = a1x * r1, b1y = a1y * r1, b1z = a1z * r1;
    float dt = b1x * a2x + b1y * a2y + b1z * a2z;
    float c2x = a2x - dt * b1x, c2y = a2y - dt * b1y, c2z = a2z - dt * b1z;
    float r2 = __builtin_amdgcn_rsqf(c2x * c2x + c2y * c2y + c2z * c2z);
    float b2x = c2x * r2, b2y = c2y * r2, b2z = c2z * r2;
    float b3x = b1y * b2z - b1z * b2y;
    float b3y = b1z * b2x - b1x * b2z;
    float b3z = b1x * b2y - b1y * b2x;
    M[0][0] = b1x; M[0][1] = b1y; M[0][2] = b1z;
    M[1][0] = b2x; M[1][1] = b2y; M[1][2] = b2z;
    M[2][0] = b3x; M[2][1] = b3y; M[2][2] = b3z;
}

// C = A @ B
__device__ __forceinline__ void matmul(const float A[3][3], const float B[3][3], float C[3][3]) {
#pragma unroll
    for (int i = 0; i < 3; ++i)
#pragma unroll
        for (int j = 0; j < 3; ++j)
            C[i][j] = A[i][0] * B[0][j] + A[i][1] * B[1][j] + A[i][2] * B[2][j];
}

// C = A^T @ B
__device__ __forceinline__ void matTmul(const float A[3][3], const float B[3][3], float C[3][3]) {
#pragma unroll
    for (int i = 0; i < 3; ++i)
#pragma unroll
        for (int j = 0; j < 3; ++j)
            C[i][j] = A[0][i] * B[0][j] + A[1][i] * B[1][j] + A[2][i] * B[2][j];
}

// atan2(y,x) for y >= 0, result in [0, pi]. Minimax atan poly on [0,1], err ~2e-8.
__device__ __forceinline__ float atan2_pos(float y, float x) {
    float ax = fabsf(x);
    float mx = fmaxf(y, ax);
    float mn = fminf(y, ax);
    float a = mn * __builtin_amdgcn_rcpf(mx);
    float s = a * a;
    float p = -0.0040540580f;
    p = fmaf(p, s, 0.0218612288f);
    p = fmaf(p, s, -0.0559098861f);
    p = fmaf(p, s, 0.0964200441f);
    p = fmaf(p, s, -0.1390853351f);
    p = fmaf(p, s, 0.1994653599f);
    p = fmaf(p, s, -0.3332985605f);
    p = fmaf(p, s, 0.9999993329f);
    float r = p * a;
    r = (y > ax) ? (1.5707963268f - r) : r;
    r = (x < 0.f) ? (3.1415926536f - r) : r;
    return r;
}

__device__ __forceinline__ void mat2aa(const float m[3][3], float* __restrict__ outp) {
    float m00 = m[0][0], m01 = m[0][1], m02 = m[0][2];
    float m10 = m[1][0], m11 = m[1][1], m12 = m[1][2];
    float m20 = m[2][0], m21 = m[2][1], m22 = m[2][2];
    float t0 = fmaxf(1.f + m00 + m11 + m22, 0.f);
    float t1 = fmaxf(1.f + m00 - m11 - m22, 0.f);
    float t2 = fmaxf(1.f - m00 + m11 - m22, 0.f);
    float t3 = fmaxf(1.f - m00 - m11 + m22, 0.f);
    // argmax over t == argmax over sqrt(t) (monotonic, same first-max ties)
    int idx = 0;
    float bt = t0;
    if (t1 > bt) { bt = t1; idx = 1; }
    if (t2 > bt) { bt = t2; idx = 2; }
    if (t3 > bt) { bt = t3; idx = 3; }
    float best = __builtin_amdgcn_sqrtf(bt);  // >= 1 always (sum of t == 4)
    float s1 = m21 - m12, s2 = m02 - m20, s3 = m10 - m01;
    float p1 = m10 + m01, p2 = m02 + m20, p3 = m12 + m21;
    float w = (idx == 0) ? bt : (idx == 1) ? s1 : (idx == 2) ? s2 : s3;
    float x = (idx == 0) ? s1 : (idx == 1) ? bt : (idx == 2) ? p1 : p2;
    float y = (idx == 0) ? s2 : (idx == 1) ? p1 : (idx == 2) ? bt : p3;
    float z = (idx == 0) ? s3 : (idx == 1) ? p2 : (idx == 2) ? p3 : bt;
    float inv = 0.5f * __builtin_amdgcn_rcpf(fmaxf(best, 0.1f));
    w *= inv; x *= inv; y *= inv; z *= inv;
    // unit quaternion: sin(half) == |v|, cos(half) == w
    float n = __builtin_amdgcn_sqrtf(x * x + y * y + z * z);
    float half = atan2_pos(n, w);
    float angle = 2.f * half;
    // angle < 1e-6 => ref's (0.5 - angle^2/48) rounds to 0.5 => inv_sh = 2
    float inv_sh = (angle < 1e-6f) ? 2.f : angle * __builtin_amdgcn_rcpf(n);
    outp[0] = x * inv_sh;
    outp[1] = y * inv_sh;
    outp[2] = z * inv_sh;
}

__global__ __launch_bounds__(256) void pose_kernel(const float* __restrict__ glb,
                                                   const float* __restrict__ ori,
                                                   float* __restrict__ out, int BT) {
    int tid = blockIdx.x * 256 + threadIdx.x;
    int e = tid >> 4;
    if (e >= BT) return;
    int l = tid & 15;

    const float* __restrict__ ge = glb + (size_t)e * 60;
    const float* __restrict__ oe = ori + (size_t)e * 36;
    float* __restrict__ oute = out + (size_t)e * 72;

    // byte-packed per-lane tables
    const unsigned long long OUT3_LO = 0x1B120F0C09060300ULL;  // joint*3, lanes 0-7
    const unsigned long long OUT3_HI = 0x393633302D2A2724ULL;  // lanes 8-15
    const unsigned long long SRCJ_LO = 0x0403121102010010ULL;
    const unsigned long long SRCJ_HI = 0x1514090813070605ULL;
    const unsigned long long PR1_LO  = 0x0403020100000000ULL;
    const unsigned long long PR1_HI  = 0x0A09080706050505ULL;
    const unsigned long long IGN3    = 0x45423F3C211E1815ULL;  // ignored joint*3, lanes 0-7

    int sh = (l & 7) * 8;
    int out3 = (int)(((l < 8 ? OUT3_LO : OUT3_HI) >> sh) & 0xFF);
    int srcj = (int)(((l < 8 ? SRCJ_LO : SRCJ_HI) >> sh) & 0xFF);
    int pr1  = (int)(((l < 8 ? PR1_LO  : PR1_HI)  >> sh) & 0xFF);

    // root = rot6d(orientation row 0) — same fp sequence in every lane
    float root[3][3];
    rot6d(oe, root);

    // F_j = root @ rot6d(src_j)
    const float* pj = (srcj & 0x10) ? (oe + (srcj & 0xF) * 6) : (ge + (srcj & 0xF) * 6);
    float T[3][3], Fj[3][3];
    rot6d(pj, T);
    matmul(root, T, Fj);

    // F_parent = root @ rot6d(src_parent)  (dummy oe when parent == root)
    const float* pp = pr1 ? (ge + (pr1 - 1) * 6) : oe;
    float Fp[3][3];
    rot6d(pp, T);
    matmul(root, T, Fp);

    // P = parent's full matrix (root for joints 1,2,3)
    float P[3][3];
#pragma unroll
    for (int i = 0; i < 3; ++i)
#pragma unroll
        for (int j = 0; j < 3; ++j)
            P[i][j] = pr1 ? Fp[i][j] : root[i][j];

    // local = P^T @ F_j ; joint 0 (lane 0): local = root itself
    float L[3][3];
    matTmul(P, Fj, L);
#pragma unroll
    for (int i = 0; i < 3; ++i)
#pragma unroll
        for (int j = 0; j < 3; ++j)
            L[i][j] = (l == 0) ? root[i][j] : L[i][j];

    mat2aa(L, oute + out3);

    // ignored joints -> exact zeros (lanes 0-7, one each)
    if (l < 8) {
        int z = (int)((IGN3 >> sh) & 0xFF);
        float* zp = oute + z;
        zp[0] = 0.f; zp[1] = 0.f; zp[2] = 0.f;
    }
}

extern "C" void kernel_launch(void* const* d_in, const int* in_sizes, int n_in,
                              void* d_out, int out_size, void* d_ws, size_t ws_size,
                              hipStream_t stream) {
    const float* glb = (const float*)d_in[0];   // (BT,10,6) f32
    const float* ori = (const float*)d_in[1];   // (BT,6,6)  f32
    float* out = (float*)d_out;                 // (BT,24,3) f32
    int BT = in_sizes[0] / 60;
    long long threads = (long long)BT * 16;
    int block = 256;
    int grid = (int)((threads + block - 1) / block);
    pose_kernel<<<grid, block, 0, stream>>>(glb, ori, out, BT);
}